// Round 3
// baseline (919.832 us; speedup 1.0000x reference)
//
#include <hip/hip_runtime.h>
#include <stdint.h>

#define B_ 8
#define S_ 4096
#define D_ 192
#define M_ (B_*S_)

typedef short v8s __attribute__((ext_vector_type(8)));
typedef float v4f __attribute__((ext_vector_type(4)));
typedef unsigned short v4us __attribute__((ext_vector_type(4)));

static __device__ __forceinline__ unsigned short f2bf(float f){
  union{float f; unsigned u;} v; v.f=f;
  unsigned u = v.u;
  unsigned r = (u + 0x7fffu + ((u>>16)&1u))>>16;
  return (unsigned short)r;
}

// ---------------- weight conversion fp32 -> bf16 ----------------
__global__ void cvt_w_kernel(const float* w0,const float* w1,const float* w2,const float* w3,
                             const float* w4,const float* w5,const float* w6,const float* w7,
                             unsigned short* dst){
  int w = blockIdx.y;
  const float* src;
  switch(w){
    case 0: src=w0; break; case 1: src=w1; break; case 2: src=w2; break; case 3: src=w3; break;
    case 4: src=w4; break; case 5: src=w5; break; case 6: src=w6; break; default: src=w7; break;
  }
  int i = blockIdx.x*256 + threadIdx.x;   // 36864 = 144*256 exact
  dst[(size_t)w*36864 + i] = f2bf(src[i]);
}

// ---------------- QKV projection (both paths): out = x @ W^T ----------------
// grid: (M/64, 6). y = path*3 + which. V stored TRANSPOSED per batch: Vt[b][d][s].
__global__ __launch_bounds__(256) void proj_kernel(
    const float* __restrict__ x, const unsigned short* __restrict__ Wb,
    unsigned short* __restrict__ QKV)   // [path][{Q,K,Vt}][...]
{
  int which = blockIdx.y % 3;
  int path  = blockIdx.y / 3;
  const size_t MD = (size_t)M_*D_;
  const unsigned short* W = Wb + (size_t)(path*4 + which)*36864;
  unsigned short* dstQ = QKV + (size_t)path*3*MD;          // Q
  unsigned short* dstK = dstQ + MD;                        // K
  unsigned short* dstV = dstQ + 2*MD;                      // Vt

  int tid = threadIdx.x;
  int wid = tid>>6, lane = tid&63;
  int lr = lane&15, lg = lane>>4, kb = lg*8;
  int m0 = blockIdx.x*64 + wid*16;
  int row = m0 + lr;

  v8s a[6];
  #pragma unroll
  for(int c=0;c<6;c++){
    const float* xp = &x[(size_t)row*D_ + c*32 + kb];
    float4 f0 = *(const float4*)xp;
    float4 f1 = *(const float4*)(xp+4);
    v8s t;
    t[0]=(short)f2bf(f0.x); t[1]=(short)f2bf(f0.y); t[2]=(short)f2bf(f0.z); t[3]=(short)f2bf(f0.w);
    t[4]=(short)f2bf(f1.x); t[5]=(short)f2bf(f1.y); t[6]=(short)f2bf(f1.z); t[7]=(short)f2bf(f1.w);
    a[c]=t;
  }
  int bidx = m0 / S_;
  int s0 = (m0 % S_) + lg*4;
  #pragma unroll
  for(int nt=0; nt<12; nt++){
    v4f acc = {0.f,0.f,0.f,0.f};
    int n = nt*16 + lr;
    #pragma unroll
    for(int c=0;c<6;c++){
      v8s b = *(const v8s*)&W[(size_t)n*D_ + c*32 + kb];
      acc = __builtin_amdgcn_mfma_f32_16x16x32_bf16(a[c], b, acc, 0,0,0);
    }
    int col = nt*16 + lr;
    if(which==2){
      v4us pk;
      pk[0]=f2bf(acc[0]); pk[1]=f2bf(acc[1]); pk[2]=f2bf(acc[2]); pk[3]=f2bf(acc[3]);
      *(v4us*)&dstV[((size_t)bidx*D_ + col)*S_ + s0] = pk;
    } else {
      unsigned short* dst = which==0? dstQ : dstK;
      int r0 = m0 + lg*4;
      #pragma unroll
      for(int r=0;r<4;r++) dst[(size_t)(r0+r)*D_ + col] = f2bf(acc[r]);
    }
  }
}

// ---------------- flash attention (both paths in one dispatch) ----------------
// grid: (S/128, B, 2). Block = 128 q rows, 4 waves x 32 rows. KV tiles of 64.
// O overwrites Q in place (block-private rows, read before written).
#define KSTR 200
#define VSTR 72
#define PSTR 68

__global__ __launch_bounds__(256,2) void attn_kernel(unsigned short* __restrict__ QKV)
{
  __shared__ __align__(16) unsigned short Klds[64*KSTR];   // 25600 B; P aliases here after QK
  __shared__ __align__(16) unsigned short Vlds[192*VSTR];  // 27648 B

  const size_t MD = (size_t)M_*D_;
  size_t poff = (size_t)blockIdx.z*3*MD;
  const unsigned short* Q  = QKV + poff;
  const unsigned short* K  = QKV + poff + MD;
  const unsigned short* Vt = QKV + poff + 2*MD;
  unsigned short* O = QKV + poff;          // alias Q

  int b = blockIdx.y;
  int q0 = blockIdx.x*128;
  int tid = threadIdx.x, wid=tid>>6, lane=tid&63;
  int lr = lane&15, lg = lane>>4, kb = lg*8;
  size_t bbase = (size_t)b*S_*D_;
  int qrow0 = q0 + wid*32;

  v8s qf[2][6];
  #pragma unroll
  for(int h=0;h<2;h++){
    size_t qrow = bbase + (size_t)(qrow0 + h*16 + lr)*D_;
    #pragma unroll
    for(int c=0;c<6;c++) qf[h][c] = *(const v8s*)&Q[qrow + c*32 + kb];
  }
  float mrow[2][4], lsum[2][4];
  v4f oacc[2][12];
  #pragma unroll
  for(int h=0;h<2;h++){
    #pragma unroll
    for(int r=0;r<4;r++){ mrow[h][r]=-3.0e38f; lsum[h][r]=0.f; }
    #pragma unroll
    for(int e=0;e<12;e++) oacc[h][e] = (v4f){0.f,0.f,0.f,0.f};
  }

  const float scale = 0.07216878364870323f;  // 1/sqrt(192)
  const size_t vbase = (size_t)b*D_*S_;      // Vt[b][d][s]
  unsigned short* Pw = Klds + wid*32*PSTR;

  // per-thread staging addresses
  int kr = tid/24 + (tid%24 >= 0 ? 0:0);     // see loop below; recompute per j
  (void)kr;

  // prologue: prefetch tile 0 into registers
  v8s kreg[6], vreg[6];
  {
    size_t kvbase = bbase;
    #pragma unroll
    for(int j=0;j<6;j++){
      int i = tid + j*256;
      int r = i/24, c8 = (i%24)*8;
      kreg[j] = *(const v8s*)&K[kvbase + (size_t)r*D_ + c8];
      int vr = i>>3, vc = (i&7)*8;
      vreg[j] = *(const v8s*)&Vt[vbase + (size_t)vr*S_ + 0*64 + vc];
    }
  }

  for(int kt=0; kt<64; kt++){
    __syncthreads();   // prev iter's LDS reads (pa/vb) complete
    #pragma unroll
    for(int j=0;j<6;j++){
      int i = tid + j*256;
      int r = i/24, c8 = (i%24)*8;
      *(v8s*)&Klds[r*KSTR + c8] = kreg[j];
      int vr = i>>3, vc = (i&7)*8;
      *(v8s*)&Vlds[vr*VSTR + vc] = vreg[j];
    }
    __syncthreads();

    // prefetch next tile into registers; drains under compute below
    if(kt < 63){
      size_t kvbase = bbase + (size_t)((kt+1)*64)*D_;
      #pragma unroll
      for(int j=0;j<6;j++){
        int i = tid + j*256;
        int r = i/24, c8 = (i%24)*8;
        kreg[j] = *(const v8s*)&K[kvbase + (size_t)r*D_ + c8];
        int vr = i>>3, vc = (i&7)*8;
        vreg[j] = *(const v8s*)&Vt[vbase + (size_t)vr*S_ + (kt+1)*64 + vc];
      }
    }

    // scores: both q-halves share each K fragment read
    v4f sacc[2][4];
    #pragma unroll
    for(int ct=0; ct<4; ct++){
      v4f s0v = {0.f,0.f,0.f,0.f}, s1v = {0.f,0.f,0.f,0.f};
      #pragma unroll
      for(int c=0;c<6;c++){
        v8s kf = *(const v8s*)&Klds[(ct*16+lr)*KSTR + c*32 + kb];
        s0v = __builtin_amdgcn_mfma_f32_16x16x32_bf16(qf[0][c], kf, s0v, 0,0,0);
        s1v = __builtin_amdgcn_mfma_f32_16x16x32_bf16(qf[1][c], kf, s1v, 0,0,0);
      }
      #pragma unroll
      for(int r=0;r<4;r++){ s0v[r]*=scale; s1v[r]*=scale; }
      sacc[0][ct]=s0v; sacc[1][ct]=s1v;
    }
    __syncthreads();   // all QK reads of Klds done before P overwrites it

    float fac[2][4];
    #pragma unroll
    for(int h=0;h<2;h++){
      #pragma unroll
      for(int r=0;r<4;r++){
        float mt = fmaxf(fmaxf(sacc[h][0][r],sacc[h][1][r]),fmaxf(sacc[h][2][r],sacc[h][3][r]));
        #pragma unroll
        for(int msk=1; msk<16; msk<<=1) mt = fmaxf(mt, __shfl_xor(mt, msk, 64));
        float mn = fmaxf(mrow[h][r], mt);
        fac[h][r] = __expf(mrow[h][r]-mn);
        mrow[h][r] = mn;
        float ps = 0.f;
        #pragma unroll
        for(int ct=0;ct<4;ct++){
          float p = __expf(sacc[h][ct][r]-mn);
          ps += p;
          Pw[(h*16 + lg*4 + r)*PSTR + ct*16 + lr] = f2bf(p);
        }
        #pragma unroll
        for(int msk=1; msk<16; msk<<=1) ps += __shfl_xor(ps, msk, 64);
        lsum[h][r] = lsum[h][r]*fac[h][r] + ps;
      }
    }
    #pragma unroll
    for(int h=0;h<2;h++){
      #pragma unroll
      for(int e=0;e<12;e++){
        #pragma unroll
        for(int r=0;r<4;r++) oacc[h][e][r]*=fac[h][r];
      }
    }

    // O += P @ V^T-tile : P-frags hoisted, V-frag shared by both halves
    v8s pa[2][2];
    #pragma unroll
    for(int h=0;h<2;h++){
      #pragma unroll
      for(int kc=0;kc<2;kc++)
        pa[h][kc] = *(const v8s*)&Pw[(h*16 + lr)*PSTR + kc*32 + kb];
    }
    #pragma unroll
    for(int e=0;e<12;e++){
      #pragma unroll
      for(int kc=0;kc<2;kc++){
        v8s vb = *(const v8s*)&Vlds[(e*16+lr)*VSTR + kc*32 + kb];
        oacc[0][e] = __builtin_amdgcn_mfma_f32_16x16x32_bf16(pa[0][kc], vb, oacc[0][e], 0,0,0);
        oacc[1][e] = __builtin_amdgcn_mfma_f32_16x16x32_bf16(pa[1][kc], vb, oacc[1][e], 0,0,0);
      }
    }
  }

  #pragma unroll
  for(int h=0;h<2;h++){
    #pragma unroll
    for(int r=0;r<4;r++) lsum[h][r] = 1.0f/lsum[h][r];
  }
  #pragma unroll
  for(int h=0;h<2;h++){
    size_t orow0 = bbase + (size_t)(qrow0 + h*16 + lg*4)*D_;
    #pragma unroll
    for(int e=0;e<12;e++){
      #pragma unroll
      for(int r=0;r<4;r++){
        O[orow0 + (size_t)r*D_ + e*16 + lr] = f2bf(oacc[h][e][r]*lsum[h][r]);
      }
    }
  }
}

// ---------------- final: R = O @ Wo^T (both), combine, column fixes ----------------
__global__ __launch_bounds__(256) void final_kernel(
  const float* __restrict__ x,
  const unsigned short* __restrict__ Or,
  const unsigned short* __restrict__ Ow,
  const unsigned short* __restrict__ WoR,
  const unsigned short* __restrict__ WoW,
  float* __restrict__ out)
{
  int tid=threadIdx.x, wid=tid>>6, lane=tid&63;
  int lr=lane&15, lg=lane>>4, kb=lg*8;
  int m0 = blockIdx.x*64 + wid*16;
  int arow = m0 + lr;
  v8s ar[6], aw[6];
  #pragma unroll
  for(int c=0;c<6;c++){
    ar[c] = *(const v8s*)&Or[(size_t)arow*D_ + c*32 + kb];
    aw[c] = *(const v8s*)&Ow[(size_t)arow*D_ + c*32 + kb];
  }
  int bidx = m0 / S_;
  float rf = x[(size_t)bidx*S_*D_ + 156];
  float wf = x[(size_t)bidx*S_*D_ + 157];
  #pragma unroll
  for(int nt=0; nt<12; nt++){
    v4f accR={0.f,0.f,0.f,0.f}, accW={0.f,0.f,0.f,0.f};
    int n = nt*16 + lr;
    #pragma unroll
    for(int c=0;c<6;c++){
      v8s br = *(const v8s*)&WoR[(size_t)n*D_ + c*32 + kb];
      accR = __builtin_amdgcn_mfma_f32_16x16x32_bf16(ar[c], br, accR,0,0,0);
      v8s bw = *(const v8s*)&WoW[(size_t)n*D_ + c*32 + kb];
      accW = __builtin_amdgcn_mfma_f32_16x16x32_bf16(aw[c], bw, accW,0,0,0);
    }
    #pragma unroll
    for(int r=0;r<4;r++){
      int row = m0 + lg*4 + r;
      int col = nt*16 + lr;
      float xv = x[(size_t)row*D_ + col];
      float val = xv + rf*(accR[r]-xv) + wf*(accW[r]-xv);
      if(col==156||col==157) val = 0.f;
      else if(col==158) val = rf+wf;
      out[(size_t)row*D_ + col] = val;
    }
  }
}

extern "C" void kernel_launch(void* const* d_in, const int* in_sizes, int n_in,
                              void* d_out, int out_size, void* d_ws, size_t ws_size,
                              hipStream_t stream) {
  const float* x = (const float*)d_in[0];
  unsigned short* ws = (unsigned short*)d_ws;
  const size_t WSZ = 36864;           // 192*192
  const size_t MD  = (size_t)M_*D_;   // 32768*192
  unsigned short* Wb  = ws;           // 8 * WSZ
  unsigned short* QKV = ws + 8*WSZ;   // [2 paths][{Q,K,Vt}][MD]; O aliases Q

  cvt_w_kernel<<<dim3(144,8),256,0,stream>>>(
      (const float*)d_in[1],(const float*)d_in[2],(const float*)d_in[3],(const float*)d_in[4],
      (const float*)d_in[5],(const float*)d_in[6],(const float*)d_in[7],(const float*)d_in[8], Wb);

  proj_kernel<<<dim3(512,6),256,0,stream>>>(x, Wb, QKV);
  attn_kernel<<<dim3(32,8,2),256,0,stream>>>(QKV);
  final_kernel<<<512,256,0,stream>>>(x, QKV /*Or=Qr*/, QKV+3*MD /*Ow=Qw*/,
                                     Wb+3*WSZ, Wb+7*WSZ, (float*)d_out);
}

// Round 5
// 648.921 us; speedup vs baseline: 1.4175x; 1.4175x over previous
//
#include <hip/hip_runtime.h>
#include <stdint.h>

#define B_ 8
#define S_ 4096
#define D_ 192
#define M_ (B_*S_)

typedef short v8s __attribute__((ext_vector_type(8)));
typedef float v4f __attribute__((ext_vector_type(4)));
typedef unsigned short v4us __attribute__((ext_vector_type(4)));

static __device__ __forceinline__ unsigned short f2bf(float f){
  union{float f; unsigned u;} v; v.f=f;
  unsigned u = v.u;
  unsigned r = (u + 0x7fffu + ((u>>16)&1u))>>16;
  return (unsigned short)r;
}

// ---------------- weight conversion fp32 -> bf16 ----------------
__global__ void cvt_w_kernel(const float* w0,const float* w1,const float* w2,const float* w3,
                             const float* w4,const float* w5,const float* w6,const float* w7,
                             unsigned short* dst){
  int w = blockIdx.y;
  const float* src;
  switch(w){
    case 0: src=w0; break; case 1: src=w1; break; case 2: src=w2; break; case 3: src=w3; break;
    case 4: src=w4; break; case 5: src=w5; break; case 6: src=w6; break; default: src=w7; break;
  }
  int i = blockIdx.x*256 + threadIdx.x;   // 36864 = 144*256 exact
  dst[(size_t)w*36864 + i] = f2bf(src[i]);
}

// ---------------- QKV projection (both paths): out = x @ W^T ----------------
// grid: (M/64, 6). y = path*3 + which. V stored TRANSPOSED per batch: Vt[b][d][s].
__global__ __launch_bounds__(256) void proj_kernel(
    const float* __restrict__ x, const unsigned short* __restrict__ Wb,
    unsigned short* __restrict__ QKV)   // [path][{Q,K,Vt}][...]
{
  int which = blockIdx.y % 3;
  int path  = blockIdx.y / 3;
  const size_t MD = (size_t)M_*D_;
  const unsigned short* W = Wb + (size_t)(path*4 + which)*36864;
  unsigned short* dstQ = QKV + (size_t)path*3*MD;          // Q
  unsigned short* dstK = dstQ + MD;                        // K
  unsigned short* dstV = dstQ + 2*MD;                      // Vt

  int tid = threadIdx.x;
  int wid = tid>>6, lane = tid&63;
  int lr = lane&15, lg = lane>>4, kb = lg*8;
  int m0 = blockIdx.x*64 + wid*16;
  int row = m0 + lr;

  v8s a[6];
  #pragma unroll
  for(int c=0;c<6;c++){
    const float* xp = &x[(size_t)row*D_ + c*32 + kb];
    float4 f0 = *(const float4*)xp;
    float4 f1 = *(const float4*)(xp+4);
    v8s t;
    t[0]=(short)f2bf(f0.x); t[1]=(short)f2bf(f0.y); t[2]=(short)f2bf(f0.z); t[3]=(short)f2bf(f0.w);
    t[4]=(short)f2bf(f1.x); t[5]=(short)f2bf(f1.y); t[6]=(short)f2bf(f1.z); t[7]=(short)f2bf(f1.w);
    a[c]=t;
  }
  int bidx = m0 / S_;
  int s0 = (m0 % S_) + lg*4;
  #pragma unroll
  for(int nt=0; nt<12; nt++){
    v4f acc = {0.f,0.f,0.f,0.f};
    int n = nt*16 + lr;
    #pragma unroll
    for(int c=0;c<6;c++){
      v8s b = *(const v8s*)&W[(size_t)n*D_ + c*32 + kb];
      acc = __builtin_amdgcn_mfma_f32_16x16x32_bf16(a[c], b, acc, 0,0,0);
    }
    int col = nt*16 + lr;
    if(which==2){
      v4us pk;
      pk[0]=f2bf(acc[0]); pk[1]=f2bf(acc[1]); pk[2]=f2bf(acc[2]); pk[3]=f2bf(acc[3]);
      *(v4us*)&dstV[((size_t)bidx*D_ + col)*S_ + s0] = pk;
    } else {
      unsigned short* dst = which==0? dstQ : dstK;
      int r0 = m0 + lg*4;
      #pragma unroll
      for(int r=0;r<4;r++) dst[(size_t)(r0+r)*D_ + col] = f2bf(acc[r]);
    }
  }
}

// ---------------- flash attention (both paths in one dispatch) ----------------
// grid: (S/128, B, 2). Block = 128 q rows, 4 waves x 32 rows. KV tiles of 64.
// O overwrites Q in place (block-private rows, read before written).
// 2 blocks/CU co-resident (LDS 53KB x 2 < 160KB, VGPR ~180 < 256).
#define KSTR 200
#define VSTR 72
#define PSTR 68

__global__ __launch_bounds__(256,2) void attn_kernel(unsigned short* __restrict__ QKV)
{
  __shared__ __align__(16) unsigned short Klds[64*KSTR];   // 25600 B; P aliases here after QK
  __shared__ __align__(16) unsigned short Vlds[192*VSTR];  // 27648 B

  const size_t MD = (size_t)M_*D_;
  size_t poff = (size_t)blockIdx.z*3*MD;
  const unsigned short* Q  = QKV + poff;
  const unsigned short* K  = QKV + poff + MD;
  const unsigned short* Vt = QKV + poff + 2*MD;
  unsigned short* O = QKV + poff;          // alias Q

  int b = blockIdx.y;
  int q0 = blockIdx.x*128;
  int tid = threadIdx.x, wid=tid>>6, lane=tid&63;
  int lr = lane&15, lg = lane>>4, kb = lg*8;
  size_t bbase = (size_t)b*S_*D_;
  int qrow0 = q0 + wid*32;

  v8s qf[2][6];
  #pragma unroll
  for(int h=0;h<2;h++){
    size_t qrow = bbase + (size_t)(qrow0 + h*16 + lr)*D_;
    #pragma unroll
    for(int c=0;c<6;c++) qf[h][c] = *(const v8s*)&Q[qrow + c*32 + kb];
  }
  float mrow[2][4], lsum[2][4];
  v4f oacc[2][12];
  #pragma unroll
  for(int h=0;h<2;h++){
    #pragma unroll
    for(int r=0;r<4;r++){ mrow[h][r]=-3.0e38f; lsum[h][r]=0.f; }
    #pragma unroll
    for(int e=0;e<12;e++) oacc[h][e] = (v4f){0.f,0.f,0.f,0.f};
  }

  const float scale = 0.07216878364870323f;  // 1/sqrt(192)
  const size_t vbase = (size_t)b*D_*S_;      // Vt[b][d][s]
  unsigned short* Pw = Klds + wid*32*PSTR;

  for(int kt=0; kt<64; kt++){
    size_t kvbase = bbase + (size_t)(kt*64)*D_;
    __syncthreads();   // prev iter's LDS reads complete
    #pragma unroll
    for(int j=0;j<6;j++){
      int i = tid + j*256;
      int r = i/24, c8 = (i%24)*8;
      *(v8s*)&Klds[r*KSTR + c8] = *(const v8s*)&K[kvbase + (size_t)r*D_ + c8];
      int vr = i>>3, vc = (i&7)*8;
      *(v8s*)&Vlds[vr*VSTR + vc] = *(const v8s*)&Vt[vbase + (size_t)vr*S_ + kt*64 + vc];
    }
    __syncthreads();

    // scores: both q-halves share each K fragment read
    v4f sacc[2][4];
    __builtin_amdgcn_s_setprio(1);
    #pragma unroll
    for(int ct=0; ct<4; ct++){
      v4f s0v = {0.f,0.f,0.f,0.f}, s1v = {0.f,0.f,0.f,0.f};
      #pragma unroll
      for(int c=0;c<6;c++){
        v8s kf = *(const v8s*)&Klds[(ct*16+lr)*KSTR + c*32 + kb];
        s0v = __builtin_amdgcn_mfma_f32_16x16x32_bf16(qf[0][c], kf, s0v, 0,0,0);
        s1v = __builtin_amdgcn_mfma_f32_16x16x32_bf16(qf[1][c], kf, s1v, 0,0,0);
      }
      #pragma unroll
      for(int r=0;r<4;r++){ s0v[r]*=scale; s1v[r]*=scale; }
      sacc[0][ct]=s0v; sacc[1][ct]=s1v;
    }
    __builtin_amdgcn_s_setprio(0);
    __syncthreads();   // all QK reads of Klds done before P overwrites it

    float fac[2][4];
    #pragma unroll
    for(int h=0;h<2;h++){
      #pragma unroll
      for(int r=0;r<4;r++){
        float mt = fmaxf(fmaxf(sacc[h][0][r],sacc[h][1][r]),fmaxf(sacc[h][2][r],sacc[h][3][r]));
        #pragma unroll
        for(int msk=1; msk<16; msk<<=1) mt = fmaxf(mt, __shfl_xor(mt, msk, 64));
        float mn = fmaxf(mrow[h][r], mt);
        fac[h][r] = __expf(mrow[h][r]-mn);
        mrow[h][r] = mn;
        float ps = 0.f;
        #pragma unroll
        for(int ct=0;ct<4;ct++){
          float p = __expf(sacc[h][ct][r]-mn);
          ps += p;
          Pw[(h*16 + lg*4 + r)*PSTR + ct*16 + lr] = f2bf(p);
        }
        #pragma unroll
        for(int msk=1; msk<16; msk<<=1) ps += __shfl_xor(ps, msk, 64);
        lsum[h][r] = lsum[h][r]*fac[h][r] + ps;
      }
    }
    #pragma unroll
    for(int h=0;h<2;h++){
      #pragma unroll
      for(int e=0;e<12;e++){
        #pragma unroll
        for(int r=0;r<4;r++) oacc[h][e][r]*=fac[h][r];
      }
    }

    // O += P @ V^T-tile : P-frags hoisted, V-frag shared by both halves
    v8s pa[2][2];
    #pragma unroll
    for(int h=0;h<2;h++){
      #pragma unroll
      for(int kc=0;kc<2;kc++)
        pa[h][kc] = *(const v8s*)&Pw[(h*16 + lr)*PSTR + kc*32 + kb];
    }
    __builtin_amdgcn_s_setprio(1);
    #pragma unroll
    for(int e=0;e<12;e++){
      #pragma unroll
      for(int kc=0;kc<2;kc++){
        v8s vb = *(const v8s*)&Vlds[(e*16+lr)*VSTR + kc*32 + kb];
        oacc[0][e] = __builtin_amdgcn_mfma_f32_16x16x32_bf16(pa[0][kc], vb, oacc[0][e], 0,0,0);
        oacc[1][e] = __builtin_amdgcn_mfma_f32_16x16x32_bf16(pa[1][kc], vb, oacc[1][e], 0,0,0);
      }
    }
    __builtin_amdgcn_s_setprio(0);
  }

  #pragma unroll
  for(int h=0;h<2;h++){
    #pragma unroll
    for(int r=0;r<4;r++) lsum[h][r] = 1.0f/lsum[h][r];
  }
  #pragma unroll
  for(int h=0;h<2;h++){
    size_t orow0 = bbase + (size_t)(qrow0 + h*16 + lg*4)*D_;
    #pragma unroll
    for(int e=0;e<12;e++){
      #pragma unroll
      for(int r=0;r<4;r++){
        O[orow0 + (size_t)r*D_ + e*16 + lr] = f2bf(oacc[h][e][r]*lsum[h][r]);
      }
    }
  }
}

// ---------------- final: R = O @ Wo^T (both), combine, column fixes ----------------
__global__ __launch_bounds__(256) void final_kernel(
  const float* __restrict__ x,
  const unsigned short* __restrict__ Or,
  const unsigned short* __restrict__ Ow,
  const unsigned short* __restrict__ WoR,
  const unsigned short* __restrict__ WoW,
  float* __restrict__ out)
{
  int tid=threadIdx.x, wid=tid>>6, lane=tid&63;
  int lr=lane&15, lg=lane>>4, kb=lg*8;
  int m0 = blockIdx.x*64 + wid*16;
  int arow = m0 + lr;
  v8s ar[6], aw[6];
  #pragma unroll
  for(int c=0;c<6;c++){
    ar[c] = *(const v8s*)&Or[(size_t)arow*D_ + c*32 + kb];
    aw[c] = *(const v8s*)&Ow[(size_t)arow*D_ + c*32 + kb];
  }
  int bidx = m0 / S_;
  float rf = x[(size_t)bidx*S_*D_ + 156];
  float wf = x[(size_t)bidx*S_*D_ + 157];
  #pragma unroll
  for(int nt=0; nt<12; nt++){
    v4f accR={0.f,0.f,0.f,0.f}, accW={0.f,0.f,0.f,0.f};
    int n = nt*16 + lr;
    #pragma unroll
    for(int c=0;c<6;c++){
      v8s br = *(const v8s*)&WoR[(size_t)n*D_ + c*32 + kb];
      accR = __builtin_amdgcn_mfma_f32_16x16x32_bf16(ar[c], br, accR,0,0,0);
      v8s bw = *(const v8s*)&WoW[(size_t)n*D_ + c*32 + kb];
      accW = __builtin_amdgcn_mfma_f32_16x16x32_bf16(aw[c], bw, accW,0,0,0);
    }
    #pragma unroll
    for(int r=0;r<4;r++){
      int row = m0 + lg*4 + r;
      int col = nt*16 + lr;
      float xv = x[(size_t)row*D_ + col];
      float val = xv + rf*(accR[r]-xv) + wf*(accW[r]-xv);
      if(col==156||col==157) val = 0.f;
      else if(col==158) val = rf+wf;
      out[(size_t)row*D_ + col] = val;
    }
  }
}

extern "C" void kernel_launch(void* const* d_in, const int* in_sizes, int n_in,
                              void* d_out, int out_size, void* d_ws, size_t ws_size,
                              hipStream_t stream) {
  const float* x = (const float*)d_in[0];
  unsigned short* ws = (unsigned short*)d_ws;
  const size_t WSZ = 36864;           // 192*192
  const size_t MD  = (size_t)M_*D_;   // 32768*192
  unsigned short* Wb  = ws;           // 8 * WSZ
  unsigned short* QKV = ws + 8*WSZ;   // [2 paths][{Q,K,Vt}][MD]; O aliases Q

  cvt_w_kernel<<<dim3(144,8),256,0,stream>>>(
      (const float*)d_in[1],(const float*)d_in[2],(const float*)d_in[3],(const float*)d_in[4],
      (const float*)d_in[5],(const float*)d_in[6],(const float*)d_in[7],(const float*)d_in[8], Wb);

  proj_kernel<<<dim3(512,6),256,0,stream>>>(x, Wb, QKV);
  attn_kernel<<<dim3(32,8,2),256,0,stream>>>(QKV);
  final_kernel<<<512,256,0,stream>>>(x, QKV /*Or=Qr*/, QKV+3*MD /*Ow=Qw*/,
                                     Wb+3*WSZ, Wb+7*WSZ, (float*)d_out);
}